// Round 5
// baseline (31.435 us; speedup 1.0000x reference)
//
#include <hip/hip_runtime.h>

#define B_ 32
#define N_ 64
#define F_ 128
#define E_ 4032
#define H_ 4
#define D_ 64

typedef __bf16 bf16x8 __attribute__((ext_vector_type(8)));
typedef __bf16 bf16x4 __attribute__((ext_vector_type(4)));
typedef float  f32x4  __attribute__((ext_vector_type(4)));

// ws layout (float offsets):
//  s_fwd @0 (8192)   s_bwd @8192 (8192)
//  wb    @24576 (128)
//  M1bf  @24704 (4096f = 8192 bf16)   [128][64]
//  Wv2bf @28800 (8192f = 16384 bf16)  [128][128]
//  Wv3bf @36992 (4096f = 8192 bf16)   [64][128]
//  u_src @61568 (262144f = 524288 bf16) [8192][64]
//  u_tgt @323712 (262144f)

// K1 (MFMA): blocks 0..255: 8 nodes/block. P = v_self@W_proj^T (wave = head),
// scores from acc registers, then U = Phat@We1half^T (u_src/u_tgt, bf16).
// Weights converted fp32->bf16 inline (each B-fragment used once).
// Blocks 256..287: weight prep for K2 (M1 = Wv1@We2, wb = Wv1@be2, bf16 Wv2/Wv3).
__global__ __launch_bounds__(256) void k_proj(
    const float* __restrict__ v_self, const float* __restrict__ W_proj,
    const float* __restrict__ We1,
    const float* __restrict__ a_fwd, const float* __restrict__ a_bwd,
    const float* __restrict__ Wv1, const float* __restrict__ We2,
    const float* __restrict__ be2, const float* __restrict__ Wv2,
    const float* __restrict__ Wv3,
    float* __restrict__ s_fwd, float* __restrict__ s_bwd,
    __bf16* __restrict__ u_src, __bf16* __restrict__ u_tgt,
    __bf16* __restrict__ M1bf, float* __restrict__ wb,
    __bf16* __restrict__ Wv2bf, __bf16* __restrict__ Wv3bf)
{
    const int t = threadIdx.x;

    if (blockIdx.x >= B_ * N_ / 8) {            // ---- prep role ----
        const int pid = (blockIdx.x - B_ * N_ / 8) * 256 + t;   // 0..8191
        const int f = pid >> 6, k = pid & 63;
        float acc = 0.f;
        for (int dd = 0; dd < 64; ++dd)
            acc += Wv1[f * 64 + dd] * We2[dd * 64 + k];   // Wv1 row wave-uniform
        M1bf[pid] = (__bf16)acc;
        float p = Wv1[f * 64 + k] * be2[k];
#pragma unroll
        for (int m = 1; m < 64; m <<= 1) p += __shfl_xor(p, m);
        if (k == 0) wb[f] = p;
        Wv2bf[pid]        = (__bf16)Wv2[pid];
        Wv2bf[pid + 8192] = (__bf16)Wv2[pid + 8192];
        Wv3bf[pid]        = (__bf16)Wv3[pid];
        return;
    }

    const int w = t >> 6, l = t & 63;
    const int q = l >> 4, lr = l & 15;
    const int node0 = blockIdx.x * 8;

    __shared__ __bf16 Av[16 * 136];      // [16 rows][128+8] (rows 8-15 zero)
    __shared__ __bf16 P_lds[8 * 288];    // [node][h][72]

    {   // stage v_self rows -> bf16; zero pad rows
        int row = t >> 5, c0 = (t & 31) * 4;
        float4 v = *(const float4*)(v_self + (size_t)(node0 + row) * 128 + c0);
        bf16x4 bv; bv[0]=(__bf16)v.x; bv[1]=(__bf16)v.y; bv[2]=(__bf16)v.z; bv[3]=(__bf16)v.w;
        *(bf16x4*)&Av[row * 136 + c0] = bv;
        bf16x4 z = {};
        *(bf16x4*)&Av[(row + 8) * 136 + c0] = z;
    }
    __syncthreads();

    // P GEMM: rows = 8 nodes (16-tile), cols w*64..+63, K = 128
    f32x4 acc[4] = {};
#pragma unroll
    for (int ks = 0; ks < 4; ++ks) {
        bf16x8 a = *(const bf16x8*)&Av[lr * 136 + ks * 32 + q * 8];
#pragma unroll
        for (int ct = 0; ct < 4; ++ct) {
            const float4* wr = (const float4*)(W_proj + (size_t)(w * 64 + ct * 16 + lr) * 128 + ks * 32 + q * 8);
            float4 w0 = wr[0], w1 = wr[1];
            bf16x8 b;
            b[0]=(__bf16)w0.x; b[1]=(__bf16)w0.y; b[2]=(__bf16)w0.z; b[3]=(__bf16)w0.w;
            b[4]=(__bf16)w1.x; b[5]=(__bf16)w1.y; b[6]=(__bf16)w1.z; b[7]=(__bf16)w1.w;
            acc[ct] = __builtin_amdgcn_mfma_f32_16x16x32_bf16(a, b, acc[ct], 0, 0, 0);
        }
    }

    // scores: s = leaky(P . a_h)/500, reduced across 16-lane col groups
    {
        float pf[4] = {0,0,0,0}, pb[4] = {0,0,0,0};
#pragma unroll
        for (int ct = 0; ct < 4; ++ct) {
            float af = a_fwd[w * 64 + ct * 16 + lr];
            float ab = a_bwd[w * 64 + ct * 16 + lr];
#pragma unroll
            for (int r = 0; r < 4; ++r) { pf[r] += acc[ct][r] * af; pb[r] += acc[ct][r] * ab; }
        }
#pragma unroll
        for (int m = 1; m < 16; m <<= 1) {
#pragma unroll
            for (int r = 0; r < 4; ++r) { pf[r] += __shfl_xor(pf[r], m); pb[r] += __shfl_xor(pb[r], m); }
        }
        if (lr == 0 && q < 2) {
#pragma unroll
            for (int r = 0; r < 4; ++r) {
                int node = q * 4 + r;
                float x = pf[r]; x = (x >= 0.f ? x : 0.2f * x) * 0.002f;
                float y = pb[r]; y = (y >= 0.f ? y : 0.2f * y) * 0.002f;
                s_fwd[(node0 + node) * 4 + w] = x;
                s_bwd[(node0 + node) * 4 + w] = y;
            }
        }
    }
    if (q < 2) {    // P rows 0..7 -> LDS bf16
#pragma unroll
        for (int ct = 0; ct < 4; ++ct)
#pragma unroll
            for (int r = 0; r < 4; ++r)
                P_lds[(q * 4 + r) * 288 + w * 72 + ct * 16 + lr] = (__bf16)acc[ct][r];
    }
    __syncthreads();

    // U GEMM: rows rr = node*4+h (32), wave: rt = w&1 row-tile, mm = w>>1 (us/ut)
    const int rt = w & 1, mm = w >> 1;
    const int rr = rt * 16 + lr, an = rr >> 2, ah = rr & 3;
    f32x4 uacc[4] = {};
#pragma unroll
    for (int ks = 0; ks < 2; ++ks) {
        bf16x8 a = *(const bf16x8*)&P_lds[an * 288 + ah * 72 + ks * 32 + q * 8];
#pragma unroll
        for (int ct = 0; ct < 4; ++ct) {
            const float4* wr = (const float4*)(We1 + (size_t)(ct * 16 + lr) * 128 + mm * 64 + ks * 32 + q * 8);
            float4 w0 = wr[0], w1 = wr[1];
            bf16x8 b;
            b[0]=(__bf16)w0.x; b[1]=(__bf16)w0.y; b[2]=(__bf16)w0.z; b[3]=(__bf16)w0.w;
            b[4]=(__bf16)w1.x; b[5]=(__bf16)w1.y; b[6]=(__bf16)w1.z; b[7]=(__bf16)w1.w;
            uacc[ct] = __builtin_amdgcn_mfma_f32_16x16x32_bf16(a, b, uacc[ct], 0, 0, 0);
        }
    }
    __bf16* up = (mm == 0) ? u_src : u_tgt;
#pragma unroll
    for (int ct = 0; ct < 4; ++ct)
#pragma unroll
        for (int r = 0; r < 4; ++r) {
            int row = rt * 16 + q * 4 + r;       // (node,h) packed
            up[(size_t)(node0 * 4 + row) * 64 + ct * 16 + lr] = (__bf16)uacc[ct][r];
        }
}

// K2 (fused edge + alpha + node-MLP): block = (b, octet of 8 receivers).
// Phase A: aij for (octet receivers x all senders) + suma; coalesced sender-
// role alpha for the octet's senders. Phase B: g accumulate, LDS-only.
// Phase C: MLP (MFMA) on the 32 (node,h) rows, g from LDS, X1/X2 reuse u_l.
__global__ __launch_bounds__(256) void k_fused(
    const float* __restrict__ s_fwd, const float* __restrict__ s_bwd,
    const __bf16* __restrict__ u_src, const __bf16* __restrict__ u_tgt,
    const float* __restrict__ be1,
    const __bf16* __restrict__ M1bf, const float* __restrict__ wb,
    const float* __restrict__ bv1,
    const __bf16* __restrict__ Wv2bf, const float* __restrict__ bv2,
    const __bf16* __restrict__ Wv3bf, const float* __restrict__ bv3,
    float* __restrict__ v_out, float* __restrict__ out_alpha)
{
    const int t = threadIdx.x;
    const int h = t >> 6, d = t & 63;            // wave = h, lane = d (also i in phase A)
    const int b = blockIdx.x >> 3, oct = blockIdx.x & 7;
    const int j0 = oct * 8;

    __shared__ float u_l[4][64][64];   // [h][i][d] fp32 (64KB); reused as X1/X2 in phase C
    __shared__ float ut_l[8][4][64];   // [j][h][d] (8KB)
    __shared__ float aij_l[4][64][8];  // [h][i][j] (8KB)
    __shared__ float suma_l[32];       // [j*4+h]
    __shared__ __bf16 g_l[32 * 72];    // [row][64+8]

    // ---- stage u_src (whole batch) and u_tgt (octet) into LDS as fp32 ----
    {
        const __bf16* ub = u_src + (size_t)b * 16384;
        for (int idx = t * 8; idx < 16384; idx += 256 * 8) {
            bf16x8 v = *(const bf16x8*)(ub + idx);
            int i = idx >> 8, col = idx & 255;
            float* dst = &u_l[col >> 6][i][col & 63];
#pragma unroll
            for (int z = 0; z < 8; ++z) dst[z] = (float)v[z];
        }
        const __bf16* utp = u_tgt + ((size_t)(b * 64 + j0)) * 256;
        {
            int idx = t * 8;   // 2048 elems, one pass
            bf16x8 v = *(const bf16x8*)(utp + idx);
            int j = idx >> 8, col = idx & 255;
            float* dst = &ut_l[j][col >> 6][col & 63];
#pragma unroll
            for (int z = 0; z < 8; ++z) dst[z] = (float)v[z];
        }
    }

    // ---- phase A: receiver-role aij + suma (lane = sender i) ----
    {
        const int i = d;
        float sfi = s_fwd[(b * 64 + i) * 4 + h];
        float areg[8];
#pragma unroll
        for (int j = 0; j < 8; ++j) {
            float sbj = s_bwd[(b * 64 + j0 + j) * 4 + h];
            float m = fmaxf(sfi, sbj);
            float eij = __expf(__expf(sfi - m));
            float eji = __expf(__expf(sbj - m));
            float aij = eij / (eij + eji);
            if (i == j0 + j) aij = 0.f;
            areg[j] = aij;
        }
        f32x4 a0 = {areg[0], areg[1], areg[2], areg[3]};
        f32x4 a1 = {areg[4], areg[5], areg[6], areg[7]};
        *(f32x4*)&aij_l[h][i][0] = a0;
        *(f32x4*)&aij_l[h][i][4] = a1;
#pragma unroll
        for (int j = 0; j < 8; ++j) {
            float sa = areg[j];
#pragma unroll
            for (int m2 = 1; m2 < 64; m2 <<= 1) sa += __shfl_xor(sa, m2);
            if (i == 0) suma_l[j * 4 + h] = sa;
        }
    }
    // ---- sender-role alpha (senders = octet, coalesced writes) ----
    if (t < 252) {
        const int jj = t >> 2, h2 = t & 3;
#pragma unroll
        for (int s = 0; s < 8; ++s) {
            int i2 = j0 + s;
            int j2 = jj + (jj >= i2 ? 1 : 0);
            float sfi = s_fwd[(b * 64 + i2) * 4 + h2];
            float sbj = s_bwd[(b * 64 + j2) * 4 + h2];
            float m = fmaxf(sfi, sbj);
            float eij = __expf(__expf(sfi - m));
            float eji = __expf(__expf(sbj - m));
            out_alpha[((size_t)b * E_ + i2 * 63 + jj) * 4 + h2] = eij / (eij + eji);
        }
    }
    __syncthreads();

    // ---- phase B: g[j,h,d] = sum_i aij*relu(aij*(us-ut)+ut+be1) ----
    {
        const float be1d = be1[d];
        float utv[8], utb[8];
#pragma unroll
        for (int j = 0; j < 8; ++j) { utv[j] = ut_l[j][h][d]; utb[j] = utv[j] + be1d; }
        float gacc[8] = {};
        for (int i = 0; i < 64; ++i) {
            float usv = u_l[h][i][d];
            f32x4 a0 = *(const f32x4*)&aij_l[h][i][0];   // uniform addr -> broadcast
            f32x4 a1 = *(const f32x4*)&aij_l[h][i][4];
#pragma unroll
            for (int j = 0; j < 4; ++j) {
                float a = a0[j];
                float hp = fmaf(a, usv - utv[j], utb[j]);
                gacc[j] = fmaf(a, fmaxf(hp, 0.f), gacc[j]);
                float a2 = a1[j];
                float hp2 = fmaf(a2, usv - utv[4 + j], utb[4 + j]);
                gacc[4 + j] = fmaf(a2, fmaxf(hp2, 0.f), gacc[4 + j]);
            }
        }
#pragma unroll
        for (int j = 0; j < 8; ++j)
            g_l[(j * 4 + h) * 72 + d] = (__bf16)gacc[j];
    }
    __syncthreads();   // also fences u_l reads before X1/X2 reuse

    // ---- phase C: MLP (MFMA), rows = 32 (node,h) ----
    __bf16* X1 = (__bf16*)&u_l[0][0][0];
    __bf16* X2 = X1 + 32 * 136;
    const int w = h, l = t & 63;
    const int q = l >> 4, lr = l & 15;
    const int rt = w & 1, ch = w >> 1;
    const int rows_base = (b * 64 + j0) * 4;

    // layer 1: cols ch*64..+63, K=64
    f32x4 acc1[4] = {};
#pragma unroll
    for (int ks = 0; ks < 2; ++ks) {
        bf16x8 a = *(const bf16x8*)&g_l[(rt * 16 + lr) * 72 + ks * 32 + q * 8];
#pragma unroll
        for (int ct = 0; ct < 4; ++ct) {
            bf16x8 bfr = *(const bf16x8*)(M1bf + (size_t)(ch * 64 + ct * 16 + lr) * 64 + ks * 32 + q * 8);
            acc1[ct] = __builtin_amdgcn_mfma_f32_16x16x32_bf16(a, bfr, acc1[ct], 0, 0, 0);
        }
    }
    float sml[4];
#pragma unroll
    for (int r = 0; r < 4; ++r) sml[r] = suma_l[rt * 16 + q * 4 + r];
#pragma unroll
    for (int ct = 0; ct < 4; ++ct) {
        int f = ch * 64 + ct * 16 + lr;
        float wbf = wb[f], b1 = bv1[f];
#pragma unroll
        for (int r = 0; r < 4; ++r) {
            float xv = acc1[ct][r] + sml[r] * wbf + b1;
            X1[(rt * 16 + q * 4 + r) * 136 + f] = (__bf16)fmaxf(xv, 0.f);
        }
    }
    __syncthreads();

    // layer 2: cols ch*64..+63, K=128
    f32x4 acc2[4] = {};
#pragma unroll
    for (int ks = 0; ks < 4; ++ks) {
        bf16x8 a = *(const bf16x8*)&X1[(rt * 16 + lr) * 136 + ks * 32 + q * 8];
#pragma unroll
        for (int ct = 0; ct < 4; ++ct) {
            bf16x8 bfr = *(const bf16x8*)(Wv2bf + (size_t)(ch * 64 + ct * 16 + lr) * 128 + ks * 32 + q * 8);
            acc2[ct] = __builtin_amdgcn_mfma_f32_16x16x32_bf16(a, bfr, acc2[ct], 0, 0, 0);
        }
    }
#pragma unroll
    for (int ct = 0; ct < 4; ++ct) {
        int f = ch * 64 + ct * 16 + lr;
        float b2 = bv2[f];
#pragma unroll
        for (int r = 0; r < 4; ++r) {
            float xv = acc2[ct][r] + b2;
            X2[(rt * 16 + q * 4 + r) * 136 + f] = (__bf16)fmaxf(xv, 0.f);
        }
    }
    __syncthreads();

    // layer 3: cols ch*32..+31 (64 total), K=128; fp32 out
    f32x4 acc3[2] = {};
#pragma unroll
    for (int ks = 0; ks < 4; ++ks) {
        bf16x8 a = *(const bf16x8*)&X2[(rt * 16 + lr) * 136 + ks * 32 + q * 8];
#pragma unroll
        for (int ct = 0; ct < 2; ++ct) {
            bf16x8 bfr = *(const bf16x8*)(Wv3bf + (size_t)(ch * 32 + ct * 16 + lr) * 128 + ks * 32 + q * 8);
            acc3[ct] = __builtin_amdgcn_mfma_f32_16x16x32_bf16(a, bfr, acc3[ct], 0, 0, 0);
        }
    }
#pragma unroll
    for (int ct = 0; ct < 2; ++ct) {
        int dd = ch * 32 + ct * 16 + lr;
        float b3 = bv3[dd];
#pragma unroll
        for (int r = 0; r < 4; ++r)
            v_out[(size_t)(rows_base + rt * 16 + q * 4 + r) * 64 + dd] = acc3[ct][r] + b3;
    }
}

extern "C" void kernel_launch(void* const* d_in, const int* in_sizes, int n_in,
                              void* d_out, int out_size, void* d_ws, size_t ws_size,
                              hipStream_t stream) {
    (void)in_sizes; (void)n_in; (void)out_size; (void)ws_size;
    const float* v_self = (const float*)d_in[0];
    const float* W_proj = (const float*)d_in[3];
    const float* a_fwd  = (const float*)d_in[4];
    const float* a_bwd  = (const float*)d_in[5];
    const float* We1    = (const float*)d_in[6];
    const float* be1    = (const float*)d_in[7];
    const float* We2    = (const float*)d_in[8];
    const float* be2    = (const float*)d_in[9];
    const float* Wv1    = (const float*)d_in[10];
    const float* bv1    = (const float*)d_in[11];
    const float* Wv2    = (const float*)d_in[12];
    const float* bv2    = (const float*)d_in[13];
    const float* Wv3    = (const float*)d_in[14];
    const float* bv3    = (const float*)d_in[15];

    float* ws = (float*)d_ws;
    float*  s_fwd = ws;
    float*  s_bwd = ws + 8192;
    float*  wb    = ws + 24576;
    __bf16* M1bf  = (__bf16*)(ws + 24704);
    __bf16* Wv2bf = (__bf16*)(ws + 28800);
    __bf16* Wv3bf = (__bf16*)(ws + 36992);
    __bf16* u_src = (__bf16*)(ws + 61568);
    __bf16* u_tgt = (__bf16*)(ws + 323712);

    float* v_out = (float*)d_out;
    float* alpha = v_out + (size_t)B_ * N_ * H_ * D_;

    hipLaunchKernelGGL(k_proj, dim3(B_ * N_ / 8 + 32), dim3(256), 0, stream,
                       v_self, W_proj, We1, a_fwd, a_bwd, Wv1, We2, be2, Wv2, Wv3,
                       s_fwd, s_bwd, u_src, u_tgt, M1bf, wb, Wv2bf, Wv3bf);
    hipLaunchKernelGGL(k_fused, dim3(B_ * N_ / 8), dim3(256), 0, stream,
                       s_fwd, s_bwd, u_src, u_tgt, be1, M1bf, wb, bv1,
                       Wv2bf, bv2, Wv3bf, bv3, v_out, alpha);
}

// Round 6
// 29.110 us; speedup vs baseline: 1.0799x; 1.0799x over previous
//
#include <hip/hip_runtime.h>

#define B_ 32
#define N_ 64
#define F_ 128
#define E_ 4032
#define H_ 4
#define D_ 64

typedef __bf16 bf16x8 __attribute__((ext_vector_type(8)));
typedef __bf16 bf16x4 __attribute__((ext_vector_type(4)));
typedef float  f32x4  __attribute__((ext_vector_type(4)));

// ws layout (float offsets):
//  s_fwd @0 (8192)   s_bwd @8192 (8192)
//  wb    @24576 (128)
//  M1bf  @24704 (4096f = 8192 bf16)   [128][64]
//  Wv2bf @28800 (8192f = 16384 bf16)  [128][128]
//  Wv3bf @36992 (4096f = 8192 bf16)   [64][128]
//  u_src @61568 (262144f = 524288 bf16) [8192][64]
//  u_tgt @323712 (262144f)

static __device__ inline bf16x8 ld_cvt8(const float* __restrict__ p) {
    float4 w0 = *(const float4*)p, w1 = *(const float4*)(p + 4);
    bf16x8 b;
    b[0]=(__bf16)w0.x; b[1]=(__bf16)w0.y; b[2]=(__bf16)w0.z; b[3]=(__bf16)w0.w;
    b[4]=(__bf16)w1.x; b[5]=(__bf16)w1.y; b[6]=(__bf16)w1.z; b[7]=(__bf16)w1.w;
    return b;
}

// K1: blocks 0..511 — single-wave (64thr) blocks, tile = 16 nodes x 1 head.
//   P(16x64,K=128) = v_self@W_proj^T slice -> scores -> U(16x128,K=64) via We1.
//   Full 16-row MFMA tiles, zero barriers across waves (block = 1 wave).
// Blocks 512..639 — prep: M1 = Wv1@We2, wb = Wv1@be2, bf16 Wv2/Wv3.
__global__ __launch_bounds__(64) void k_proj(
    const float* __restrict__ v_self, const float* __restrict__ W_proj,
    const float* __restrict__ We1,
    const float* __restrict__ a_fwd, const float* __restrict__ a_bwd,
    const float* __restrict__ Wv1, const float* __restrict__ We2,
    const float* __restrict__ be2, const float* __restrict__ Wv2,
    const float* __restrict__ Wv3,
    float* __restrict__ s_fwd, float* __restrict__ s_bwd,
    __bf16* __restrict__ u_src, __bf16* __restrict__ u_tgt,
    __bf16* __restrict__ M1bf, float* __restrict__ wb,
    __bf16* __restrict__ Wv2bf, __bf16* __restrict__ Wv3bf)
{
    const int t = threadIdx.x;
    const int blk = blockIdx.x;

    if (blk >= 512) {                           // ---- prep role ----
        const int f = blk - 512;                // 0..127 (wave-uniform)
        const int k = t;                        // 0..63
        const int pid = f * 64 + k;
        float acc = 0.f;
        for (int dd = 0; dd < 64; ++dd)
            acc += Wv1[f * 64 + dd] * We2[dd * 64 + k];
        M1bf[pid] = (__bf16)acc;
        float p = Wv1[f * 64 + k] * be2[k];
#pragma unroll
        for (int m = 1; m < 64; m <<= 1) p += __shfl_xor(p, m);
        if (k == 0) wb[f] = p;
        Wv2bf[pid]        = (__bf16)Wv2[pid];
        Wv2bf[pid + 8192] = (__bf16)Wv2[pid + 8192];
        Wv3bf[pid]        = (__bf16)Wv3[pid];
        return;
    }

    const int tile = blk >> 2, w = blk & 3;     // 128 node-tiles x 4 heads
    const int node0 = tile * 16;
    const int q = t >> 4, lr = t & 15;

    __shared__ __bf16 P_lds[16 * 72];           // [node][72] (144B stride, 16B-aligned)

    // P GEMM: 16 nodes x 64 cols (head w), K = 128; A and B from global + cvt
    f32x4 acc[4] = {};
#pragma unroll
    for (int ks = 0; ks < 4; ++ks) {
        bf16x8 a = ld_cvt8(v_self + (size_t)(node0 + lr) * 128 + ks * 32 + q * 8);
#pragma unroll
        for (int ct = 0; ct < 4; ++ct) {
            bf16x8 bb = ld_cvt8(W_proj + (size_t)(w * 64 + ct * 16 + lr) * 128 + ks * 32 + q * 8);
            acc[ct] = __builtin_amdgcn_mfma_f32_16x16x32_bf16(a, bb, acc[ct], 0, 0, 0);
        }
    }

    // scores: s = leaky(P . a_h)/500 ; acc[ct][r] = P[node 4q+r][col ct*16+lr]
    {
        float pf[4] = {0,0,0,0}, pb[4] = {0,0,0,0};
#pragma unroll
        for (int ct = 0; ct < 4; ++ct) {
            float af = a_fwd[w * 64 + ct * 16 + lr];
            float ab = a_bwd[w * 64 + ct * 16 + lr];
#pragma unroll
            for (int r = 0; r < 4; ++r) { pf[r] += acc[ct][r] * af; pb[r] += acc[ct][r] * ab; }
        }
#pragma unroll
        for (int m = 1; m < 16; m <<= 1) {
#pragma unroll
            for (int r = 0; r < 4; ++r) { pf[r] += __shfl_xor(pf[r], m); pb[r] += __shfl_xor(pb[r], m); }
        }
        if (lr == 0) {
#pragma unroll
            for (int r = 0; r < 4; ++r) {
                float x = pf[r]; x = (x >= 0.f ? x : 0.2f * x) * 0.002f;
                float y = pb[r]; y = (y >= 0.f ? y : 0.2f * y) * 0.002f;
                s_fwd[(node0 + q * 4 + r) * 4 + w] = x;
                s_bwd[(node0 + q * 4 + r) * 4 + w] = y;
            }
        }
    }

    // P -> LDS (bf16), then U GEMM: 16 nodes x (64 src + 64 tgt), K = 64
#pragma unroll
    for (int ct = 0; ct < 4; ++ct)
#pragma unroll
        for (int r = 0; r < 4; ++r)
            P_lds[(q * 4 + r) * 72 + ct * 16 + lr] = (__bf16)acc[ct][r];
    __syncthreads();

    f32x4 us[4] = {}, ut[4] = {};
#pragma unroll
    for (int ks = 0; ks < 2; ++ks) {
        bf16x8 a = *(const bf16x8*)&P_lds[lr * 72 + ks * 32 + q * 8];
#pragma unroll
        for (int ct = 0; ct < 4; ++ct) {
            bf16x8 bs = ld_cvt8(We1 + (size_t)(ct * 16 + lr) * 128 + ks * 32 + q * 8);
            us[ct] = __builtin_amdgcn_mfma_f32_16x16x32_bf16(a, bs, us[ct], 0, 0, 0);
            bf16x8 bt = ld_cvt8(We1 + (size_t)(ct * 16 + lr) * 128 + 64 + ks * 32 + q * 8);
            ut[ct] = __builtin_amdgcn_mfma_f32_16x16x32_bf16(a, bt, ut[ct], 0, 0, 0);
        }
    }
#pragma unroll
    for (int ct = 0; ct < 4; ++ct)
#pragma unroll
        for (int r = 0; r < 4; ++r) {
            size_t row = (size_t)(node0 + q * 4 + r) * 4 + w;   // (node, head)
            u_src[row * 64 + ct * 16 + lr] = (__bf16)us[ct][r];
            u_tgt[row * 64 + ct * 16 + lr] = (__bf16)ut[ct][r];
        }
}

// K2 (fused edge + alpha + MLP): block = (b, quartet of 4 receivers), 512 blocks,
// ~19KB LDS -> 2 blocks/CU (8 waves/CU). No u_src staging (L2-hot, read per-i,
// amortized over 4 receivers). Phase C: one 16-row MFMA tile (4 nodes x 4 heads).
__global__ __launch_bounds__(256) void k_fused(
    const float* __restrict__ s_fwd, const float* __restrict__ s_bwd,
    const __bf16* __restrict__ u_src, const __bf16* __restrict__ u_tgt,
    const float* __restrict__ be1,
    const __bf16* __restrict__ M1bf, const float* __restrict__ wb,
    const float* __restrict__ bv1,
    const __bf16* __restrict__ Wv2bf, const float* __restrict__ bv2,
    const __bf16* __restrict__ Wv3bf, const float* __restrict__ bv3,
    float* __restrict__ v_out, float* __restrict__ out_alpha)
{
    const int t = threadIdx.x;
    const int h = t >> 6, d = t & 63;           // wave = head, lane = d (= i in phase A)
    const int b = blockIdx.x >> 4, quad = blockIdx.x & 15;
    const int j0 = quad * 4;

    __shared__ float  ut_l[4][4][64];   // [j][h][d]
    __shared__ float  aij_l[4][64][4];  // [h][i][j]
    __shared__ float  suma_l[16];       // [j*4+h]
    __shared__ __bf16 g_l[16 * 72];
    __shared__ __bf16 X1[16 * 136];
    __shared__ __bf16 X2[16 * 136];

    // stage u_tgt for the quartet (1024 bf16)
    {
        int idx = t * 4;
        bf16x4 v = *(const bf16x4*)(u_tgt + (size_t)(b * 64 + j0) * 256 + idx);
        int j = idx >> 8, col = idx & 255;
        f32x4 f;
#pragma unroll
        for (int z = 0; z < 4; ++z) f[z] = (float)v[z];
        *(f32x4*)&ut_l[j][col >> 6][col & 63] = f;
    }

    // phase A: aij (lane = sender i) + suma
    {
        const int i = d;
        float sfi = s_fwd[(b * 64 + i) * 4 + h];
        float areg[4];
#pragma unroll
        for (int jl = 0; jl < 4; ++jl) {
            float sbj = s_bwd[(b * 64 + j0 + jl) * 4 + h];
            float m = fmaxf(sfi, sbj);
            float eij = __expf(__expf(sfi - m));
            float eji = __expf(__expf(sbj - m));
            float aij = eij / (eij + eji);
            if (i == j0 + jl) aij = 0.f;
            areg[jl] = aij;
        }
        f32x4 a4 = {areg[0], areg[1], areg[2], areg[3]};
        *(f32x4*)&aij_l[h][i][0] = a4;
#pragma unroll
        for (int jl = 0; jl < 4; ++jl) {
            float sa = areg[jl];
#pragma unroll
            for (int m2 = 1; m2 < 64; m2 <<= 1) sa += __shfl_xor(sa, m2);
            if (i == 0) suma_l[jl * 4 + h] = sa;
        }
    }
    // sender-role alpha (senders = the quartet, coalesced writes)
    if (t < 252) {
        const int jj = t >> 2, h2 = t & 3;
#pragma unroll
        for (int s = 0; s < 4; ++s) {
            int i2 = j0 + s;
            int j2 = jj + (jj >= i2 ? 1 : 0);
            float sfi = s_fwd[(b * 64 + i2) * 4 + h2];
            float sbj = s_bwd[(b * 64 + j2) * 4 + h2];
            float m = fmaxf(sfi, sbj);
            float eij = __expf(__expf(sfi - m));
            float eji = __expf(__expf(sbj - m));
            out_alpha[((size_t)b * E_ + i2 * 63 + jj) * 4 + h2] = eij / (eij + eji);
        }
    }
    __syncthreads();

    // phase B: g[jl,h,d] = sum_i aij * relu(aij*(us-ut) + ut + be1); u_src from L2
    {
        const float be1d = be1[d];
        float utv[4], utb[4];
#pragma unroll
        for (int jl = 0; jl < 4; ++jl) { utv[jl] = ut_l[jl][h][d]; utb[jl] = utv[jl] + be1d; }
        float gacc[4] = {};
        const __bf16* usp = u_src + ((size_t)(b * 64) * 4 + h) * 64 + d;
#pragma unroll 4
        for (int i = 0; i < 64; ++i) {
            float usv = (float)usp[i * 256];
            f32x4 a4 = *(const f32x4*)&aij_l[h][i][0];   // uniform addr -> broadcast
#pragma unroll
            for (int jl = 0; jl < 4; ++jl) {
                float a = a4[jl];
                float hp = fmaf(a, usv - utv[jl], utb[jl]);
                gacc[jl] = fmaf(a, fmaxf(hp, 0.f), gacc[jl]);
            }
        }
#pragma unroll
        for (int jl = 0; jl < 4; ++jl)
            g_l[(jl * 4 + h) * 72 + d] = (__bf16)gacc[jl];
    }
    __syncthreads();

    // phase C: MLP on one 16-row tile; wave w covers cols [w*32, w*32+32) (L1/L2), [w*16,+16) (L3)
    const int w = h;
    const int q = d >> 4, lr = d & 15;

    // layer 1: K=64, out 128 cols
    f32x4 acc1[2] = {};
#pragma unroll
    for (int ks = 0; ks < 2; ++ks) {
        bf16x8 a = *(const bf16x8*)&g_l[lr * 72 + ks * 32 + q * 8];
#pragma unroll
        for (int c = 0; c < 2; ++c) {
            int ct = w * 2 + c;
            bf16x8 bb = *(const bf16x8*)(M1bf + (size_t)(ct * 16 + lr) * 64 + ks * 32 + q * 8);
            acc1[c] = __builtin_amdgcn_mfma_f32_16x16x32_bf16(a, bb, acc1[c], 0, 0, 0);
        }
    }
    float sml[4];
#pragma unroll
    for (int r = 0; r < 4; ++r) sml[r] = suma_l[q * 4 + r];
#pragma unroll
    for (int c = 0; c < 2; ++c) {
        int f = (w * 2 + c) * 16 + lr;
        float wbf = wb[f], b1 = bv1[f];
#pragma unroll
        for (int r = 0; r < 4; ++r) {
            float xv = acc1[c][r] + sml[r] * wbf + b1;
            X1[(q * 4 + r) * 136 + f] = (__bf16)fmaxf(xv, 0.f);
        }
    }
    __syncthreads();

    // layer 2: K=128, out 128 cols
    f32x4 acc2[2] = {};
#pragma unroll
    for (int ks = 0; ks < 4; ++ks) {
        bf16x8 a = *(const bf16x8*)&X1[lr * 136 + ks * 32 + q * 8];
#pragma unroll
        for (int c = 0; c < 2; ++c) {
            int ct = w * 2 + c;
            bf16x8 bb = *(const bf16x8*)(Wv2bf + (size_t)(ct * 16 + lr) * 128 + ks * 32 + q * 8);
            acc2[c] = __builtin_amdgcn_mfma_f32_16x16x32_bf16(a, bb, acc2[c], 0, 0, 0);
        }
    }
#pragma unroll
    for (int c = 0; c < 2; ++c) {
        int f = (w * 2 + c) * 16 + lr;
        float b2 = bv2[f];
#pragma unroll
        for (int r = 0; r < 4; ++r) {
            float xv = acc2[c][r] + b2;
            X2[(q * 4 + r) * 136 + f] = (__bf16)fmaxf(xv, 0.f);
        }
    }
    __syncthreads();

    // layer 3: K=128, out 64 cols; fp32 out
    f32x4 acc3 = {};
#pragma unroll
    for (int ks = 0; ks < 4; ++ks) {
        bf16x8 a = *(const bf16x8*)&X2[lr * 136 + ks * 32 + q * 8];
        bf16x8 bb = *(const bf16x8*)(Wv3bf + (size_t)(w * 16 + lr) * 128 + ks * 32 + q * 8);
        acc3 = __builtin_amdgcn_mfma_f32_16x16x32_bf16(a, bb, acc3, 0, 0, 0);
    }
    {
        int dd = w * 16 + lr;
        float b3 = bv3[dd];
        size_t rows_base = (size_t)(b * 64 + j0) * 4;
#pragma unroll
        for (int r = 0; r < 4; ++r)
            v_out[(rows_base + q * 4 + r) * 64 + dd] = acc3[r] + b3;
    }
}

extern "C" void kernel_launch(void* const* d_in, const int* in_sizes, int n_in,
                              void* d_out, int out_size, void* d_ws, size_t ws_size,
                              hipStream_t stream) {
    (void)in_sizes; (void)n_in; (void)out_size; (void)ws_size;
    const float* v_self = (const float*)d_in[0];
    const float* W_proj = (const float*)d_in[3];
    const float* a_fwd  = (const float*)d_in[4];
    const float* a_bwd  = (const float*)d_in[5];
    const float* We1    = (const float*)d_in[6];
    const float* be1    = (const float*)d_in[7];
    const float* We2    = (const float*)d_in[8];
    const float* be2    = (const float*)d_in[9];
    const float* Wv1    = (const float*)d_in[10];
    const float* bv1    = (const float*)d_in[11];
    const float* Wv2    = (const float*)d_in[12];
    const float* bv2    = (const float*)d_in[13];
    const float* Wv3    = (const float*)d_in[14];
    const float* bv3    = (const float*)d_in[15];

    float* ws = (float*)d_ws;
    float*  s_fwd = ws;
    float*  s_bwd = ws + 8192;
    float*  wb    = ws + 24576;
    __bf16* M1bf  = (__bf16*)(ws + 24704);
    __bf16* Wv2bf = (__bf16*)(ws + 28800);
    __bf16* Wv3bf = (__bf16*)(ws + 36992);
    __bf16* u_src = (__bf16*)(ws + 61568);
    __bf16* u_tgt = (__bf16*)(ws + 323712);

    float* v_out = (float*)d_out;
    float* alpha = v_out + (size_t)B_ * N_ * H_ * D_;

    hipLaunchKernelGGL(k_proj, dim3(512 + 128), dim3(64), 0, stream,
                       v_self, W_proj, We1, a_fwd, a_bwd, Wv1, We2, be2, Wv2, Wv3,
                       s_fwd, s_bwd, u_src, u_tgt, M1bf, wb, Wv2bf, Wv3bf);
    hipLaunchKernelGGL(k_fused, dim3(B_ * N_ / 4), dim3(256), 0, stream,
                       s_fwd, s_bwd, u_src, u_tgt, be1, M1bf, wb, bv1,
                       Wv2bf, bv2, Wv3bf, bv3, v_out, alpha);
}

// Round 7
// 26.141 us; speedup vs baseline: 1.2025x; 1.1136x over previous
//
#include <hip/hip_runtime.h>

#define B_ 32
#define N_ 64
#define F_ 128
#define E_ 4032
#define H_ 4
#define D_ 64

typedef __bf16 bf16x8 __attribute__((ext_vector_type(8)));
typedef __bf16 bf16x4 __attribute__((ext_vector_type(4)));
typedef float  f32x4  __attribute__((ext_vector_type(4)));

// ws layout (float offsets):
//  s_fwd @0 (8192)   s_bwd @8192 (8192)
//  wb    @24576 (128)
//  M1bf  @24704 (4096f = 8192 bf16)   [128][64]
//  Wv2bf @28800 (8192f = 16384 bf16)  [128][128]
//  Wv3bf @36992 (4096f = 8192 bf16)   [64][128]
//  u_src @61568 (262144f = 524288 bf16) [8192][64]
//  u_tgt @323712 (262144f)

static __device__ inline bf16x8 ld_cvt8(const float* __restrict__ p) {
    float4 w0 = *(const float4*)p, w1 = *(const float4*)(p + 4);
    bf16x8 b;
    b[0]=(__bf16)w0.x; b[1]=(__bf16)w0.y; b[2]=(__bf16)w0.z; b[3]=(__bf16)w0.w;
    b[4]=(__bf16)w1.x; b[5]=(__bf16)w1.y; b[6]=(__bf16)w1.z; b[7]=(__bf16)w1.w;
    return b;
}

// K1: blocks 0..255 — two (tile,head) units per 256-thr block. Unit = 2 waves:
//   P(16x64,K=128) split K-halves across the wave pair (LDS fp32 reduce), then
//   wave0 -> U_src, wave1 -> U_tgt (K=64 each). 1024 waves total (4/CU).
// Blocks 256..287 — prep (unroll-8): M1 = Wv1@We2, wb = Wv1@be2, bf16 Wv2/Wv3.
__global__ __launch_bounds__(256) void k_proj(
    const float* __restrict__ v_self, const float* __restrict__ W_proj,
    const float* __restrict__ We1,
    const float* __restrict__ a_fwd, const float* __restrict__ a_bwd,
    const float* __restrict__ Wv1, const float* __restrict__ We2,
    const float* __restrict__ be2, const float* __restrict__ Wv2,
    const float* __restrict__ Wv3,
    float* __restrict__ s_fwd, float* __restrict__ s_bwd,
    __bf16* __restrict__ u_src, __bf16* __restrict__ u_tgt,
    __bf16* __restrict__ M1bf, float* __restrict__ wb,
    __bf16* __restrict__ Wv2bf, __bf16* __restrict__ Wv3bf)
{
    const int t = threadIdx.x;
    const int blk = blockIdx.x;

    if (blk >= 256) {                           // ---- prep role ----
        const int pid = (blk - 256) * 256 + t;  // 0..8191
        const int f = pid >> 6, k = pid & 63;
        float acc = 0.f;
#pragma unroll 8
        for (int dd = 0; dd < 64; ++dd)
            acc += Wv1[f * 64 + dd] * We2[dd * 64 + k];
        M1bf[pid] = (__bf16)acc;
        float p = Wv1[f * 64 + k] * be2[k];
#pragma unroll
        for (int m = 1; m < 64; m <<= 1) p += __shfl_xor(p, m);
        if (k == 0) wb[f] = p;
        Wv2bf[pid]        = (__bf16)Wv2[pid];
        Wv2bf[pid + 8192] = (__bf16)Wv2[pid + 8192];
        Wv3bf[pid]        = (__bf16)Wv3[pid];
        return;
    }

    const int u = t >> 7;                       // unit within block (0,1)
    const int wsub = (t >> 6) & 1;              // wave within unit
    const int l = t & 63, q = l >> 4, lr = l & 15;
    const int gu = blk * 2 + u;                 // 0..511
    const int tile = gu >> 2, w = gu & 3;       // 128 node-tiles x 4 heads
    const int node0 = tile * 16;

    __shared__ float  accp[2][16][68];          // K-half partials (fp32)
    __shared__ __bf16 P_lds[2][16 * 72];

    // P GEMM: this wave does K-chunks {2*wsub, 2*wsub+1} (K=64 of 128)
    f32x4 acc[4] = {};
#pragma unroll
    for (int kk = 0; kk < 2; ++kk) {
        int ks = wsub * 2 + kk;
        bf16x8 a = ld_cvt8(v_self + (size_t)(node0 + lr) * 128 + ks * 32 + q * 8);
#pragma unroll
        for (int ct = 0; ct < 4; ++ct) {
            bf16x8 bb = ld_cvt8(W_proj + (size_t)(w * 64 + ct * 16 + lr) * 128 + ks * 32 + q * 8);
            acc[ct] = __builtin_amdgcn_mfma_f32_16x16x32_bf16(a, bb, acc[ct], 0, 0, 0);
        }
    }
    if (wsub == 1) {
#pragma unroll
        for (int ct = 0; ct < 4; ++ct)
#pragma unroll
            for (int r = 0; r < 4; ++r)
                accp[u][q * 4 + r][ct * 16 + lr] = acc[ct][r];
    }
    __syncthreads();

    if (wsub == 0) {
        // reduce K-halves; scores; P -> LDS bf16
        float pf[4] = {0,0,0,0}, pb[4] = {0,0,0,0};
#pragma unroll
        for (int ct = 0; ct < 4; ++ct) {
            float af = a_fwd[w * 64 + ct * 16 + lr];
            float ab = a_bwd[w * 64 + ct * 16 + lr];
#pragma unroll
            for (int r = 0; r < 4; ++r) {
                float full = acc[ct][r] + accp[u][q * 4 + r][ct * 16 + lr];
                acc[ct][r] = full;
                pf[r] += full * af;
                pb[r] += full * ab;
            }
        }
#pragma unroll
        for (int m = 1; m < 16; m <<= 1) {
#pragma unroll
            for (int r = 0; r < 4; ++r) { pf[r] += __shfl_xor(pf[r], m); pb[r] += __shfl_xor(pb[r], m); }
        }
        if (lr == 0) {
#pragma unroll
            for (int r = 0; r < 4; ++r) {
                float x = pf[r]; x = (x >= 0.f ? x : 0.2f * x) * 0.002f;
                float y = pb[r]; y = (y >= 0.f ? y : 0.2f * y) * 0.002f;
                s_fwd[(node0 + q * 4 + r) * 4 + w] = x;
                s_bwd[(node0 + q * 4 + r) * 4 + w] = y;
            }
        }
#pragma unroll
        for (int ct = 0; ct < 4; ++ct)
#pragma unroll
            for (int r = 0; r < 4; ++r)
                P_lds[u][(q * 4 + r) * 72 + ct * 16 + lr] = (__bf16)acc[ct][r];
    }
    __syncthreads();

    // U GEMM: wave wsub does (0 -> u_src, 1 -> u_tgt), K = 64
    const int mm = wsub;
    f32x4 uacc[4] = {};
#pragma unroll
    for (int ks = 0; ks < 2; ++ks) {
        bf16x8 a = *(const bf16x8*)&P_lds[u][lr * 72 + ks * 32 + q * 8];
#pragma unroll
        for (int ct = 0; ct < 4; ++ct) {
            bf16x8 bb = ld_cvt8(We1 + (size_t)(ct * 16 + lr) * 128 + mm * 64 + ks * 32 + q * 8);
            uacc[ct] = __builtin_amdgcn_mfma_f32_16x16x32_bf16(a, bb, uacc[ct], 0, 0, 0);
        }
    }
    __bf16* up = (mm == 0) ? u_src : u_tgt;
#pragma unroll
    for (int ct = 0; ct < 4; ++ct)
#pragma unroll
        for (int r = 0; r < 4; ++r) {
            size_t row = (size_t)(node0 + q * 4 + r) * 4 + w;   // (node, head)
            up[row * 64 + ct * 16 + lr] = (__bf16)uacc[ct][r];
        }
}

// K2 (fused edge + alpha + MLP): block = (b, quartet of 4 receivers), 512 blocks.
// Phase B reads u_src from L2 (unroll-8). Phase C: one 16-row MFMA tile.
__global__ __launch_bounds__(256) void k_fused(
    const float* __restrict__ s_fwd, const float* __restrict__ s_bwd,
    const __bf16* __restrict__ u_src, const __bf16* __restrict__ u_tgt,
    const float* __restrict__ be1,
    const __bf16* __restrict__ M1bf, const float* __restrict__ wb,
    const float* __restrict__ bv1,
    const __bf16* __restrict__ Wv2bf, const float* __restrict__ bv2,
    const __bf16* __restrict__ Wv3bf, const float* __restrict__ bv3,
    float* __restrict__ v_out, float* __restrict__ out_alpha)
{
    const int t = threadIdx.x;
    const int h = t >> 6, d = t & 63;           // wave = head, lane = d (= i in phase A)
    const int b = blockIdx.x >> 4, quad = blockIdx.x & 15;
    const int j0 = quad * 4;

    __shared__ float  ut_l[4][4][64];   // [j][h][d]
    __shared__ float  aij_l[4][64][4];  // [h][i][j]
    __shared__ float  suma_l[16];       // [j*4+h]
    __shared__ __bf16 g_l[16 * 72];
    __shared__ __bf16 X1[16 * 136];
    __shared__ __bf16 X2[16 * 136];

    // stage u_tgt for the quartet (1024 bf16)
    {
        int idx = t * 4;
        bf16x4 v = *(const bf16x4*)(u_tgt + (size_t)(b * 64 + j0) * 256 + idx);
        int j = idx >> 8, col = idx & 255;
        f32x4 f;
#pragma unroll
        for (int z = 0; z < 4; ++z) f[z] = (float)v[z];
        *(f32x4*)&ut_l[j][col >> 6][col & 63] = f;
    }

    // phase A: aij (lane = sender i) + suma
    {
        const int i = d;
        float sfi = s_fwd[(b * 64 + i) * 4 + h];
        float areg[4];
#pragma unroll
        for (int jl = 0; jl < 4; ++jl) {
            float sbj = s_bwd[(b * 64 + j0 + jl) * 4 + h];
            float m = fmaxf(sfi, sbj);
            float eij = __expf(__expf(sfi - m));
            float eji = __expf(__expf(sbj - m));
            float aij = eij / (eij + eji);
            if (i == j0 + jl) aij = 0.f;
            areg[jl] = aij;
        }
        f32x4 a4 = {areg[0], areg[1], areg[2], areg[3]};
        *(f32x4*)&aij_l[h][i][0] = a4;
#pragma unroll
        for (int jl = 0; jl < 4; ++jl) {
            float sa = areg[jl];
#pragma unroll
            for (int m2 = 1; m2 < 64; m2 <<= 1) sa += __shfl_xor(sa, m2);
            if (i == 0) suma_l[jl * 4 + h] = sa;
        }
    }
    // sender-role alpha (senders = the quartet, coalesced writes)
    if (t < 252) {
        const int jj = t >> 2, h2 = t & 3;
#pragma unroll
        for (int s = 0; s < 4; ++s) {
            int i2 = j0 + s;
            int j2 = jj + (jj >= i2 ? 1 : 0);
            float sfi = s_fwd[(b * 64 + i2) * 4 + h2];
            float sbj = s_bwd[(b * 64 + j2) * 4 + h2];
            float m = fmaxf(sfi, sbj);
            float eij = __expf(__expf(sfi - m));
            float eji = __expf(__expf(sbj - m));
            out_alpha[((size_t)b * E_ + i2 * 63 + jj) * 4 + h2] = eij / (eij + eji);
        }
    }
    __syncthreads();

    // phase B: g[jl,h,d] = sum_i aij * relu(aij*(us-ut) + ut + be1); u_src from L2
    {
        const float be1d = be1[d];
        float utv[4], utb[4];
#pragma unroll
        for (int jl = 0; jl < 4; ++jl) { utv[jl] = ut_l[jl][h][d]; utb[jl] = utv[jl] + be1d; }
        float gacc[4] = {};
        const __bf16* usp = u_src + ((size_t)(b * 64) * 4 + h) * 64 + d;
#pragma unroll 8
        for (int i = 0; i < 64; ++i) {
            float usv = (float)usp[i * 256];
            f32x4 a4 = *(const f32x4*)&aij_l[h][i][0];   // uniform addr -> broadcast
#pragma unroll
            for (int jl = 0; jl < 4; ++jl) {
                float a = a4[jl];
                float hp = fmaf(a, usv - utv[jl], utb[jl]);
                gacc[jl] = fmaf(a, fmaxf(hp, 0.f), gacc[jl]);
            }
        }
#pragma unroll
        for (int jl = 0; jl < 4; ++jl)
            g_l[(jl * 4 + h) * 72 + d] = (__bf16)gacc[jl];
    }
    __syncthreads();

    // phase C: MLP on one 16-row tile; wave w covers its column slice
    const int w = h;
    const int q = d >> 4, lr = d & 15;

    // layer 1: K=64, out 128 cols
    f32x4 acc1[2] = {};
#pragma unroll
    for (int ks = 0; ks < 2; ++ks) {
        bf16x8 a = *(const bf16x8*)&g_l[lr * 72 + ks * 32 + q * 8];
#pragma unroll
        for (int c = 0; c < 2; ++c) {
            int ct = w * 2 + c;
            bf16x8 bb = *(const bf16x8*)(M1bf + (size_t)(ct * 16 + lr) * 64 + ks * 32 + q * 8);
            acc1[c] = __builtin_amdgcn_mfma_f32_16x16x32_bf16(a, bb, acc1[c], 0, 0, 0);
        }
    }
    float sml[4];
#pragma unroll
    for (int r = 0; r < 4; ++r) sml[r] = suma_l[q * 4 + r];
#pragma unroll
    for (int c = 0; c < 2; ++c) {
        int f = (w * 2 + c) * 16 + lr;
        float wbf = wb[f], b1 = bv1[f];
#pragma unroll
        for (int r = 0; r < 4; ++r) {
            float xv = acc1[c][r] + sml[r] * wbf + b1;
            X1[(q * 4 + r) * 136 + f] = (__bf16)fmaxf(xv, 0.f);
        }
    }
    __syncthreads();

    // layer 2: K=128, out 128 cols
    f32x4 acc2[2] = {};
#pragma unroll
    for (int ks = 0; ks < 4; ++ks) {
        bf16x8 a = *(const bf16x8*)&X1[lr * 136 + ks * 32 + q * 8];
#pragma unroll
        for (int c = 0; c < 2; ++c) {
            int ct = w * 2 + c;
            bf16x8 bb = *(const bf16x8*)(Wv2bf + (size_t)(ct * 16 + lr) * 128 + ks * 32 + q * 8);
            acc2[c] = __builtin_amdgcn_mfma_f32_16x16x32_bf16(a, bb, acc2[c], 0, 0, 0);
        }
    }
#pragma unroll
    for (int c = 0; c < 2; ++c) {
        int f = (w * 2 + c) * 16 + lr;
        float b2 = bv2[f];
#pragma unroll
        for (int r = 0; r < 4; ++r) {
            float xv = acc2[c][r] + b2;
            X2[(q * 4 + r) * 136 + f] = (__bf16)fmaxf(xv, 0.f);
        }
    }
    __syncthreads();

    // layer 3: K=128, out 64 cols; fp32 out
    f32x4 acc3 = {};
#pragma unroll
    for (int ks = 0; ks < 4; ++ks) {
        bf16x8 a = *(const bf16x8*)&X2[lr * 136 + ks * 32 + q * 8];
        bf16x8 bb = *(const bf16x8*)(Wv3bf + (size_t)(w * 16 + lr) * 128 + ks * 32 + q * 8);
        acc3 = __builtin_amdgcn_mfma_f32_16x16x32_bf16(a, bb, acc3, 0, 0, 0);
    }
    {
        int dd = w * 16 + lr;
        float b3 = bv3[dd];
        size_t rows_base = (size_t)(b * 64 + j0) * 4;
#pragma unroll
        for (int r = 0; r < 4; ++r)
            v_out[(rows_base + q * 4 + r) * 64 + dd] = acc3[r] + b3;
    }
}

extern "C" void kernel_launch(void* const* d_in, const int* in_sizes, int n_in,
                              void* d_out, int out_size, void* d_ws, size_t ws_size,
                              hipStream_t stream) {
    (void)in_sizes; (void)n_in; (void)out_size; (void)ws_size;
    const float* v_self = (const float*)d_in[0];
    const float* W_proj = (const float*)d_in[3];
    const float* a_fwd  = (const float*)d_in[4];
    const float* a_bwd  = (const float*)d_in[5];
    const float* We1    = (const float*)d_in[6];
    const float* be1    = (const float*)d_in[7];
    const float* We2    = (const float*)d_in[8];
    const float* be2    = (const float*)d_in[9];
    const float* Wv1    = (const float*)d_in[10];
    const float* bv1    = (const float*)d_in[11];
    const float* Wv2    = (const float*)d_in[12];
    const float* bv2    = (const float*)d_in[13];
    const float* Wv3    = (const float*)d_in[14];
    const float* bv3    = (const float*)d_in[15];

    float* ws = (float*)d_ws;
    float*  s_fwd = ws;
    float*  s_bwd = ws + 8192;
    float*  wb    = ws + 24576;
    __bf16* M1bf  = (__bf16*)(ws + 24704);
    __bf16* Wv2bf = (__bf16*)(ws + 28800);
    __bf16* Wv3bf = (__bf16*)(ws + 36992);
    __bf16* u_src = (__bf16*)(ws + 61568);
    __bf16* u_tgt = (__bf16*)(ws + 323712);

    float* v_out = (float*)d_out;
    float* alpha = v_out + (size_t)B_ * N_ * H_ * D_;

    hipLaunchKernelGGL(k_proj, dim3(256 + 32), dim3(256), 0, stream,
                       v_self, W_proj, We1, a_fwd, a_bwd, Wv1, We2, be2, Wv2, Wv3,
                       s_fwd, s_bwd, u_src, u_tgt, M1bf, wb, Wv2bf, Wv3bf);
    hipLaunchKernelGGL(k_fused, dim3(B_ * N_ / 4), dim3(256), 0, stream,
                       s_fwd, s_bwd, u_src, u_tgt, be1, M1bf, wb, bv1,
                       Wv2bf, bv2, Wv3bf, bv3, v_out, alpha);
}